// Round 11
// baseline (5104.369 us; speedup 1.0000x reference)
//
#include <hip/hip_runtime.h>
#include <math.h>

typedef unsigned short u16;
typedef unsigned int   u32;
typedef unsigned long long u64;
typedef __bf16 bf16x8 __attribute__((ext_vector_type(8)));
typedef float  f32x16 __attribute__((ext_vector_type(16)));

#define BB 256
#define TT 256
#define HD 256
#define ED 128
#define NSTEPS 265

/* ws layout (u32 units):
   [0, H_U32)        : h ping-pong, packed bf16 hi|lo<<16  [10][2][256][256]
   [CTR_OFF, +512)   : 8 barrier counters (128B padded) + gen broadcast @+256
   [XP_OFF, +XP_U32) : packed x  [256][256][8]
   [WT_OFF, ...)     : 32x32-fragment-ordered bf16 weights                  */
#define H_U32   (10 * 2 * BB * HD)
#define CTR_OFF H_U32
#define CTR_U32 512
#define XP_OFF  (H_U32 + CTR_U32)
#define XP_U32  (BB * TT * 8)
#define WT_OFF  (XP_OFF + XP_U32)

__constant__ size_t g_woff[10] = {0ul,589824ul,1638400ul,2686976ul,3735552ul,
                                  4784128ul,5177344ul,5439488ul,5701632ul,5963776ul};
__constant__ int g_cb[11] = {0,73728,204800,335872,466944,598016,
                             647168,679936,712704,745472,778240};

__device__ __forceinline__ u16 f2bf_hi(float f) {
    u32 u = __float_as_uint(f);
    u32 r = (u + 0x7FFFu + ((u >> 16) & 1u)) >> 16;
    return (u16)r;
}
__device__ __forceinline__ float bf2f(u16 h) { return __uint_as_float(((u32)h) << 16); }
__device__ __forceinline__ float sigmoidf_(float v) { return 1.0f / (1.0f + expf(-v)); }

__global__ __launch_bounds__(256) void zero_state(u32* wsd) {
    const int n = XP_OFF;
    for (int i = blockIdx.x * blockDim.x + threadIdx.x; i < n; i += gridDim.x * blockDim.x)
        wsd[i] = 0u;
}

__global__ __launch_bounds__(256) void conv_x(const float* __restrict__ x, u32* __restrict__ wsd) {
    u32* xp = wsd + XP_OFF;
    for (int i = blockIdx.x * blockDim.x + threadIdx.x; i < XP_U32; i += gridDim.x * blockDim.x) {
        float v = x[i];
        u16 hi = f2bf_hi(v);
        u16 lo = f2bf_hi(v - bf2f(hi));
        xp[i] = (u32)hi | ((u32)lo << 16);
    }
}

/* weights -> bf16 hi/lo, 32x32x16-MFMA fragment order:
   chunk = ((jt*4 + jh*2 + p)*NK2 + s)*64 + lane ; element e:
   row = gate*hd + jt*16 + jh*8 + jl,  gate=(lane&31)>>3, jl=(lane&31)&7;
   k   = s*16 + (lane>>5)*8 + e.  (A-operand: row=lane&31, k=(lane>>5)*8+e) */
__global__ __launch_bounds__(256) void conv_all(
    const float* __restrict__ w_ih0_1, const float* __restrict__ w_ihr_1,
    const float* __restrict__ w_hh_1,
    const float* __restrict__ w_ih0_2, const float* __restrict__ w_ihr_2,
    const float* __restrict__ w_hh_2,
    u32* __restrict__ wsd)
{
    __bf16* dst0 = (__bf16*)(wsd + WT_OFF);
    const int nch = 778240;
    for (int ci = blockIdx.x * blockDim.x + threadIdx.x; ci < nch;
         ci += gridDim.x * blockDim.x) {
        int l = 0;
        while (ci >= g_cb[l + 1]) ++l;
        int di = ci - g_cb[l];

        const int hd  = (l < 5) ? 256 : 128;
        const int din = (l == 0) ? 32 : ((l < 6) ? 256 : 128);
        const int xw  = (l == 0) ? 8 : din;
        const int Kp  = din + hd;
        const int NK2 = Kp >> 4;

        const float *wih, *whh; int wihld, whhld;
        if (l == 0)      { wih = w_ih0_1;                                whh = w_hh_1;
                           wihld = 8;   whhld = 256; }
        else if (l < 5)  { wih = w_ihr_1 + (size_t)(l - 1) * 1024 * 256; whh = w_hh_1 + (size_t)l * 1024 * 256;
                           wihld = 256; whhld = 256; }
        else if (l == 5) { wih = w_ih0_2;                                whh = w_hh_2;
                           wihld = 256; whhld = 128; }
        else             { wih = w_ihr_2 + (size_t)(l - 6) * 512 * 128;  whh = w_hh_2 + (size_t)(l - 5) * 512 * 128;
                           wihld = 128; whhld = 128; }

        int lane = di & 63;
        int rem  = di >> 6;
        int s    = rem % NK2;
        int rem2 = rem / NK2;
        int p    = rem2 & 1;
        int jh   = (rem2 >> 1) & 1;
        int jt   = rem2 >> 2;
        int r31  = lane & 31;
        int gate = r31 >> 3, jl = r31 & 7;
        int kh   = (lane >> 5) * 8;
        int row  = gate * hd + jt * 16 + jh * 8 + jl;

        bf16x8 o8;
        #pragma unroll
        for (int e = 0; e < 8; ++e) {
            int k = s * 16 + kh + e;
            float v = 0.0f;
            if (k < xw) v = wih[(size_t)row * wihld + k];
            else if (k >= din && k < Kp) v = whh[(size_t)row * whhld + (k - din)];
            __bf16 h = (__bf16)v;
            o8[e] = p ? (__bf16)(v - (float)h) : h;
        }
        *(bf16x8*)(dst0 + g_woff[l] + (size_t)di * 8) = o8;
    }
}

__device__ __forceinline__ void unpack8(const uint4& a, const uint4& b, bf16x8& bh, bf16x8& bl) {
    union { u32 u[4]; bf16x8 v; } H, L;
    H.u[0] = (a.x & 0xFFFFu) | (a.y << 16);
    H.u[1] = (a.z & 0xFFFFu) | (a.w << 16);
    H.u[2] = (b.x & 0xFFFFu) | (b.y << 16);
    H.u[3] = (b.z & 0xFFFFu) | (b.w << 16);
    L.u[0] = (a.x >> 16) | (a.y & 0xFFFF0000u);
    L.u[1] = (a.z >> 16) | (a.w & 0xFFFF0000u);
    L.u[2] = (b.x >> 16) | (b.y & 0xFFFF0000u);
    L.u[3] = (b.z >> 16) | (b.w & 0xFFFF0000u);
    bh = H.v; bl = L.v;
}

/* persistent step loop; wave = 8j x 32b x ALL 4 gates via 32x32x16 MFMA */
template<int NKI, int NKT, bool ISL0>
__device__ void run_persist(int l, int bid, int xcd, int jt, int bt, int hd,
    const float* __restrict__ bias, u32* __restrict__ hbuf, u32* __restrict__ ctr,
    const u32* __restrict__ xp, float* __restrict__ out, const u16* __restrict__ A_sh)
{
    constexpr int NK2 = NKT * 2;
    constexpr int DIN = NKI * 32;
    constexpr int RS  = (NK2 < 8) ? NK2 : 8;

    const int tid   = threadIdx.x;
    const int lane  = tid & 63;
    const int wv    = tid >> 6;
    const int bg    = wv >> 1;          /* batch group 0..3 (32 b each) */
    const int jh    = wv & 1;           /* j half 0..1 (8 j each) */
    const int r31   = lane & 31;
    const int kh    = (lane >> 5) * 8;
    const int b     = bt * 128 + bg * 32 + r31;
    const int jbase = jt * 16 + jh * 8 + (lane >> 5) * 4;

    const int hiBase = ((jh * 2 + 0) * NK2) * 512 + lane * 8;
    const int loBase = ((jh * 2 + 1) * NK2) * 512 + lane * 8;

    float bias_r[4][4];
    #pragma unroll
    for (int g = 0; g < 4; ++g) {
        float4 v = *(const float4*)&bias[g * hd + jbase];
        bias_r[g][0] = v.x; bias_r[g][1] = v.y; bias_r[g][2] = v.z; bias_r[g][3] = v.w;
    }

    float4 cv = make_float4(0.f, 0.f, 0.f, 0.f);
    const int lm = (l > 0) ? (l - 1) : 0;

    for (int w = 0; w < NSTEPS; ++w) {
        const int t = w - l;
        if (t >= 0 && t < TT) {
            const u32* hin   = hbuf + ((size_t)lm * 2 + (t & 1)) * (BB * HD);
            const u32* hprev = hbuf + ((size_t)l * 2 + ((t & 1) ^ 1)) * (BB * HD);
            u32*       hout  = hbuf + ((size_t)l * 2 + (t & 1)) * (BB * HD);

            auto ldB = [&](int s, uint4& qa, uint4& qb) {
                if constexpr (ISL0) {
                    if (s == 0) {
                        if (lane < 32) {
                            const uint4* p = (const uint4*)(xp + ((size_t)b * TT + t) * 8);
                            qa = p[0]; qb = p[1];
                        } else { qa = make_uint4(0,0,0,0); qb = make_uint4(0,0,0,0); }
                    } else if (s == 1) {
                        qa = make_uint4(0,0,0,0); qb = make_uint4(0,0,0,0);
                    } else {
                        const u32* p = hprev + (size_t)b * HD + (s * 16 + kh - 32);
                        qa = *(const uint4*)p; qb = *(const uint4*)(p + 4);
                    }
                } else {
                    const int k0 = s * 16 + kh;
                    const u32* p = (k0 < DIN) ? (hin + (size_t)b * HD + k0)
                                              : (hprev + (size_t)b * HD + (k0 - DIN));
                    qa = *(const uint4*)p; qb = *(const uint4*)(p + 4);
                }
            };

            f32x16 acc;
            #pragma unroll
            for (int i = 0; i < 16; ++i) acc[i] = 0.f;

            uint4 ra[RS], rb[RS];
            #pragma unroll
            for (int i = 0; i < RS; ++i) ldB(i, ra[i], rb[i]);

            #pragma unroll
            for (int s = 0; s < NK2; ++s) {
                bf16x8 bh, bl;
                unpack8(ra[s % RS], rb[s % RS], bh, bl);
                if (s + RS < NK2) ldB(s + RS, ra[s % RS], rb[s % RS]);

                bf16x8 ah = *(const bf16x8*)&A_sh[hiBase + s * 512];
                bf16x8 al = *(const bf16x8*)&A_sh[loBase + s * 512];

                acc = __builtin_amdgcn_mfma_f32_32x32x16_bf16(ah, bh, acc, 0, 0, 0);
                acc = __builtin_amdgcn_mfma_f32_32x32x16_bf16(ah, bl, acc, 0, 0, 0);
                acc = __builtin_amdgcn_mfma_f32_32x32x16_bf16(al, bh, acc, 0, 0, 0);
            }

            /* epilogue: lane holds gates {i,f,g,o} at regs {g*4+jj}, j = jbase+jj */
            float4 hv;
            {
                float i_, f_, g_, o_;
                i_ = sigmoidf_(acc[0]  + bias_r[0][0]); f_ = sigmoidf_(acc[4]  + bias_r[1][0]);
                g_ = tanhf   (acc[8]  + bias_r[2][0]); o_ = sigmoidf_(acc[12] + bias_r[3][0]);
                cv.x = fmaf(f_, cv.x, i_ * g_); hv.x = o_ * tanhf(cv.x);
                i_ = sigmoidf_(acc[1]  + bias_r[0][1]); f_ = sigmoidf_(acc[5]  + bias_r[1][1]);
                g_ = tanhf   (acc[9]  + bias_r[2][1]); o_ = sigmoidf_(acc[13] + bias_r[3][1]);
                cv.y = fmaf(f_, cv.y, i_ * g_); hv.y = o_ * tanhf(cv.y);
                i_ = sigmoidf_(acc[2]  + bias_r[0][2]); f_ = sigmoidf_(acc[6]  + bias_r[1][2]);
                g_ = tanhf   (acc[10] + bias_r[2][2]); o_ = sigmoidf_(acc[14] + bias_r[3][2]);
                cv.z = fmaf(f_, cv.z, i_ * g_); hv.z = o_ * tanhf(cv.z);
                i_ = sigmoidf_(acc[3]  + bias_r[0][3]); f_ = sigmoidf_(acc[7]  + bias_r[1][3]);
                g_ = tanhf   (acc[11] + bias_r[2][3]); o_ = sigmoidf_(acc[15] + bias_r[3][3]);
                cv.w = fmaf(f_, cv.w, i_ * g_); hv.w = o_ * tanhf(cv.w);
            }

            u32 pk0, pk1, pk2, pk3;
            {
                u16 h0 = f2bf_hi(hv.x); pk0 = (u32)h0 | ((u32)f2bf_hi(hv.x - bf2f(h0)) << 16);
                u16 h1 = f2bf_hi(hv.y); pk1 = (u32)h1 | ((u32)f2bf_hi(hv.y - bf2f(h1)) << 16);
                u16 h2 = f2bf_hi(hv.z); pk2 = (u32)h2 | ((u32)f2bf_hi(hv.z - bf2f(h2)) << 16);
                u16 h3 = f2bf_hi(hv.w); pk3 = (u32)h3 | ((u32)f2bf_hi(hv.w - bf2f(h3)) << 16);
            }
            u64* hp = (u64*)(hout + (size_t)b * HD + jbase);
            __hip_atomic_store(hp + 0, (u64)pk0 | ((u64)pk1 << 32), __ATOMIC_RELAXED, __HIP_MEMORY_SCOPE_AGENT);
            __hip_atomic_store(hp + 1, (u64)pk2 | ((u64)pk3 << 32), __ATOMIC_RELAXED, __HIP_MEMORY_SCOPE_AGENT);

            if (l == 9 && t == TT - 1)
                *(float4*)&out[(size_t)b * ED + jbase] = hv;
        }

        /* ---- global barrier: per-XCD arrivals; block 0 aggregates and
           broadcasts a generation word; everyone polls one word ---- */
        __syncthreads();
        if (tid == 0) {
            __hip_atomic_fetch_add(&ctr[xcd * 32], 1u,
                                   __ATOMIC_RELAXED, __HIP_MEMORY_SCOPE_AGENT);
            const u32 w1 = (u32)(w + 1);
            if (bid == 0) {
                for (int it = 0; it < (1 << 22); ++it) {
                    bool ok = true;
                    #pragma unroll
                    for (int r = 0; r < 8; ++r) {
                        u32 tgt = ((r == 7) ? 16u : 32u) * w1;
                        ok &= (__hip_atomic_load(&ctr[r * 32], __ATOMIC_RELAXED,
                                                 __HIP_MEMORY_SCOPE_AGENT) >= tgt);
                    }
                    if (ok) break;
                    __builtin_amdgcn_s_sleep(1);
                }
                __hip_atomic_store(&ctr[256], w1, __ATOMIC_RELAXED, __HIP_MEMORY_SCOPE_AGENT);
            } else {
                for (int it = 0; it < (1 << 22); ++it) {
                    if (__hip_atomic_load(&ctr[256], __ATOMIC_RELAXED,
                                          __HIP_MEMORY_SCOPE_AGENT) >= w1) break;
                    __builtin_amdgcn_s_sleep(1);
                }
            }
            __builtin_amdgcn_fence(__ATOMIC_ACQUIRE, "agent");  /* inv, no writeback */
        }
        __syncthreads();
    }
}

/* Grid 256 (16 idle), 512 thr = 8 waves (2 jh x 4 bg).
   bid%8 = XCD heuristic (correctness placement-agnostic):
     xcd 0-4 : layer = xcd   (16 jt x 2 bt)
     xcd 5   : layers 5,6 ; xcd 6 : layers 7,8 ; xcd 7 : layer 9 (16 blk) */
__global__ __launch_bounds__(512, 2) void lstm_persist(
    const float* __restrict__ b_1, const float* __restrict__ b_2,
    u32* __restrict__ wsd, float* __restrict__ out)
{
    __shared__ __align__(16) u16 A_sh[65536];   /* 128 KiB */

    const int bid = blockIdx.x;
    const int xcd = bid & 7, slot = bid >> 3;
    int l, jt, bt;
    if (xcd < 5)      { l = xcd;               bt = slot >> 4;        jt = slot & 15; }
    else if (xcd == 5){ l = 5 + (slot >> 4);   bt = (slot >> 3) & 1;  jt = slot & 7; }
    else if (xcd == 6){ l = 7 + (slot >> 4);   bt = (slot >> 3) & 1;  jt = slot & 7; }
    else              { if (slot >= 16) return; l = 9; bt = slot >> 3; jt = slot & 7; }

    const int hd  = (l < 5) ? 256 : 128;
    const int din = (l == 0) ? 32 : ((l < 6) ? 256 : 128);
    const int NK2 = (din + hd) >> 4;
    const float* bias = (l < 5) ? (b_1 + l * 1024) : (b_2 + (l - 5) * 512);

    u32* hbuf = wsd;
    u32* ctr  = wsd + CTR_OFF;
    const u32* xp = wsd + XP_OFF;
    const u16* wt = (const u16*)(wsd + WT_OFF);

    /* one-time: copy this block's fragment-ordered weight slice into LDS */
    {
        const uint4* src = (const uint4*)(wt + g_woff[l] + (size_t)jt * 4 * NK2 * 512);
        uint4* dst = (uint4*)A_sh;
        const int n4 = NK2 * 256;
        for (int i = threadIdx.x; i < n4; i += 512) dst[i] = src[i];
    }
    __syncthreads();

    if (l == 0)
        run_persist<1, 9, true >(l, bid, xcd, jt, bt, hd, bias, hbuf, ctr, xp, out, A_sh);
    else if (l < 5)
        run_persist<8, 16, false>(l, bid, xcd, jt, bt, hd, bias, hbuf, ctr, xp, out, A_sh);
    else if (l == 5)
        run_persist<8, 12, false>(l, bid, xcd, jt, bt, hd, bias, hbuf, ctr, xp, out, A_sh);
    else
        run_persist<4, 8, false>(l, bid, xcd, jt, bt, hd, bias, hbuf, ctr, xp, out, A_sh);
}

extern "C" void kernel_launch(void* const* d_in, const int* in_sizes, int n_in,
                              void* d_out, int out_size, void* d_ws, size_t ws_size,
                              hipStream_t stream) {
    const float* x       = (const float*)d_in[0];
    const float* w_ih0_1 = (const float*)d_in[1];
    const float* w_ihr_1 = (const float*)d_in[2];
    const float* w_hh_1  = (const float*)d_in[3];
    const float* b_1     = (const float*)d_in[4];
    const float* w_ih0_2 = (const float*)d_in[5];
    const float* w_ihr_2 = (const float*)d_in[6];
    const float* w_hh_2  = (const float*)d_in[7];
    const float* b_2     = (const float*)d_in[8];
    u32*   wsd = (u32*)d_ws;
    float* out = (float*)d_out;

    hipLaunchKernelGGL(zero_state, dim3(1024), dim3(256), 0, stream, wsd);
    hipLaunchKernelGGL(conv_all, dim3(1024), dim3(256), 0, stream,
                       w_ih0_1, w_ihr_1, w_hh_1, w_ih0_2, w_ihr_2, w_hh_2, wsd);
    hipLaunchKernelGGL(conv_x, dim3(256), dim3(256), 0, stream, x, wsd);
    hipLaunchKernelGGL(lstm_persist, dim3(256), dim3(512), 0, stream,
                       b_1, b_2, wsd, out);
}